// Round 2
// baseline (41.272 us; speedup 1.0000x reference)
//
#include <hip/hip_runtime.h>
#include <hip/hip_cooperative_groups.h>

namespace cg = cooperative_groups;

// CenterLoss: loss = sum_b ||x[b] - centers[labels[b]]||^2 / BATCH
// x: [1024, 512] f32, labels: [1024] i32, centers: [100000, 512] f32
// out: scalar f32.

#define BATCH 1024
#define FEAT 512
#define NBLK 256   // 1 block per CU, fully co-resident -> grid.sync valid
#define NTHR 256   // 4 waves, 1 row per wave, 4 rows per block

__global__ __launch_bounds__(NTHR) void cl_fused(
    const float* __restrict__ x,
    const int* __restrict__ labels,
    const float* __restrict__ centers,
    float* __restrict__ out,
    float* __restrict__ partial) {
    const int b = blockIdx.x;
    const int t = threadIdx.x;
    const int wave = t >> 6;   // 0..3
    const int lane = t & 63;
    const int row = b * 4 + wave;

    const int lab = labels[row];
    const float4* xr = reinterpret_cast<const float4*>(x + (size_t)row * FEAT);
    const float4* cr = reinterpret_cast<const float4*>(centers + (size_t)lab * FEAT);

    // 512 floats/row = 128 float4; 64 lanes * 2 iters.
    float4 a0 = xr[lane];
    float4 c0 = cr[lane];
    float4 a1 = xr[lane + 64];
    float4 c1 = cr[lane + 64];

    float dx0 = a0.x - c0.x, dy0 = a0.y - c0.y, dz0 = a0.z - c0.z, dw0 = a0.w - c0.w;
    float dx1 = a1.x - c1.x, dy1 = a1.y - c1.y, dz1 = a1.z - c1.z, dw1 = a1.w - c1.w;
    float s = dx0 * dx0 + dy0 * dy0 + dz0 * dz0 + dw0 * dw0
            + dx1 * dx1 + dy1 * dy1 + dz1 * dz1 + dw1 * dw1;

    #pragma unroll
    for (int off = 32; off > 0; off >>= 1)
        s += __shfl_down(s, off, 64);

    __shared__ float wsum[4];
    if (lane == 0) wsum[wave] = s;
    __syncthreads();
    if (t == 0) partial[b] = wsum[0] + wsum[1] + wsum[2] + wsum[3];

    cg::this_grid().sync();

    if (b == 0) {
        float v = partial[t];  // 256 partials, 256 threads
        #pragma unroll
        for (int off = 32; off > 0; off >>= 1)
            v += __shfl_down(v, off, 64);
        __shared__ float fsum[4];
        if (lane == 0) fsum[wave] = v;
        __syncthreads();
        if (t == 0) out[0] = (fsum[0] + fsum[1] + fsum[2] + fsum[3]) * (1.0f / (float)BATCH);
    }
}

// ---- fallback path (2 launches), used only if cooperative launch fails ----
__global__ __launch_bounds__(128) void cl_row_kernel(
    const float* __restrict__ x,
    const int* __restrict__ labels,
    const float* __restrict__ centers,
    float* __restrict__ partial) {
    const int row = blockIdx.x;
    const int t = threadIdx.x;  // 0..127
    const int lab = labels[row];
    const float4* xr = reinterpret_cast<const float4*>(x + (size_t)row * FEAT);
    const float4* cr = reinterpret_cast<const float4*>(centers + (size_t)lab * FEAT);
    float4 a = xr[t];
    float4 c = cr[t];
    float dx = a.x - c.x, dy = a.y - c.y, dz = a.z - c.z, dw = a.w - c.w;
    float s = dx * dx + dy * dy + dz * dz + dw * dw;
    #pragma unroll
    for (int off = 32; off > 0; off >>= 1)
        s += __shfl_down(s, off, 64);
    __shared__ float wsum[2];
    if ((t & 63) == 0) wsum[t >> 6] = s;
    __syncthreads();
    if (t == 0) partial[row] = wsum[0] + wsum[1];
}

__global__ __launch_bounds__(256) void cl_final_kernel(
    const float* __restrict__ partial,
    float* __restrict__ out) {
    const int t = threadIdx.x;
    float4 v = reinterpret_cast<const float4*>(partial)[t];
    float s = v.x + v.y + v.z + v.w;
    #pragma unroll
    for (int off = 32; off > 0; off >>= 1)
        s += __shfl_down(s, off, 64);
    __shared__ float wsum[4];
    if ((t & 63) == 0) wsum[t >> 6] = s;
    __syncthreads();
    if (t == 0) out[0] = (wsum[0] + wsum[1] + wsum[2] + wsum[3]) * (1.0f / (float)BATCH);
}

extern "C" void kernel_launch(void* const* d_in, const int* in_sizes, int n_in,
                              void* d_out, int out_size, void* d_ws, size_t ws_size,
                              hipStream_t stream) {
    const float* x = (const float*)d_in[0];
    const int* labels = (const int*)d_in[1];
    const float* centers = (const float*)d_in[2];
    float* out = (float*)d_out;
    float* partial = (float*)d_ws;  // NBLK * 4 bytes

    void* args[] = {(void*)&x, (void*)&labels, (void*)&centers, (void*)&out, (void*)&partial};
    hipError_t err = hipLaunchCooperativeKernel((const void*)cl_fused,
                                                dim3(NBLK), dim3(NTHR),
                                                args, 0, stream);
    if (err != hipSuccess) {
        // Fallback: classic 2-kernel path.
        cl_row_kernel<<<BATCH, 128, 0, stream>>>(x, labels, centers, partial);
        cl_final_kernel<<<1, 256, 0, stream>>>(partial, out);
    }
}

// Round 3
// 12.099 us; speedup vs baseline: 3.4111x; 3.4111x over previous
//
#include <hip/hip_runtime.h>

// CenterLoss: loss = sum_b ||x[b] - centers[labels[b]]||^2 / BATCH
// x: [1024, 512] f32, labels: [1024] i32, centers: [100000, 512] f32
// out: scalar f32.
//
// Single-launch producer/consumer: 256 blocks, each computes 4 rows and
// publishes a partial sum; block 0 spin-waits on per-block MAGIC flags
// (agent-scope atomics -> coherent across XCDs), reduces deterministically,
// writes the scalar, and resets flags to 0 for the next graph replay.
// No counter memset needed: poison 0xAAAAAAAA != MAGIC, and flags are
// left at 0 by each call.

#define BATCH 1024
#define FEAT 512
#define NBLK 256
#define NTHR 256
#define MAGIC 0x13572468u

__global__ __launch_bounds__(NTHR) void cl_fused_flags(
    const float* __restrict__ x,
    const int* __restrict__ labels,
    const float* __restrict__ centers,
    float* __restrict__ out,
    float* __restrict__ partial,
    unsigned int* __restrict__ flags) {
    const int b = blockIdx.x;
    const int t = threadIdx.x;
    const int wave = t >> 6;   // 0..3
    const int lane = t & 63;
    const int row = b * 4 + wave;

    const int lab = labels[row];
    const float4* xr = reinterpret_cast<const float4*>(x + (size_t)row * FEAT);
    const float4* cr = reinterpret_cast<const float4*>(centers + (size_t)lab * FEAT);

    // 512 floats/row = 128 float4 = 64 lanes * 2
    float4 a0 = xr[lane];
    float4 c0 = cr[lane];
    float4 a1 = xr[lane + 64];
    float4 c1 = cr[lane + 64];

    float dx0 = a0.x - c0.x, dy0 = a0.y - c0.y, dz0 = a0.z - c0.z, dw0 = a0.w - c0.w;
    float dx1 = a1.x - c1.x, dy1 = a1.y - c1.y, dz1 = a1.z - c1.z, dw1 = a1.w - c1.w;
    float s = dx0 * dx0 + dy0 * dy0 + dz0 * dz0 + dw0 * dw0
            + dx1 * dx1 + dy1 * dy1 + dz1 * dz1 + dw1 * dw1;

    #pragma unroll
    for (int off = 32; off > 0; off >>= 1)
        s += __shfl_down(s, off, 64);

    __shared__ float wsum[4];
    if (lane == 0) wsum[wave] = s;
    __syncthreads();
    const float blocksum = wsum[0] + wsum[1] + wsum[2] + wsum[3];

    if (b != 0) {
        if (t == 0) {
            __hip_atomic_store(&partial[b], blocksum, __ATOMIC_RELAXED, __HIP_MEMORY_SCOPE_AGENT);
            __hip_atomic_store(&flags[b], MAGIC, __ATOMIC_RELEASE, __HIP_MEMORY_SCOPE_AGENT);
        }
        return;
    }

    // --- block 0: consumer ---
    float v;
    if (t == 0) {
        v = blocksum;
    } else {
        while (__hip_atomic_load(&flags[t], __ATOMIC_ACQUIRE, __HIP_MEMORY_SCOPE_AGENT) != MAGIC) {
            // spin
        }
        v = __hip_atomic_load(&partial[t], __ATOMIC_RELAXED, __HIP_MEMORY_SCOPE_AGENT);
        // reset for next replay (poison-safe restart state)
        __hip_atomic_store(&flags[t], 0u, __ATOMIC_RELAXED, __HIP_MEMORY_SCOPE_AGENT);
    }

    #pragma unroll
    for (int off = 32; off > 0; off >>= 1)
        v += __shfl_down(v, off, 64);

    __shared__ float fsum[4];
    if (lane == 0) fsum[wave] = v;
    __syncthreads();
    if (t == 0)
        out[0] = (fsum[0] + fsum[1] + fsum[2] + fsum[3]) * (1.0f / (float)BATCH);
}

extern "C" void kernel_launch(void* const* d_in, const int* in_sizes, int n_in,
                              void* d_out, int out_size, void* d_ws, size_t ws_size,
                              hipStream_t stream) {
    const float* x = (const float*)d_in[0];
    const int* labels = (const int*)d_in[1];
    const float* centers = (const float*)d_in[2];
    float* out = (float*)d_out;
    float* partial = (float*)d_ws;                         // NBLK floats
    unsigned int* flags = (unsigned int*)(partial + NBLK); // NBLK u32

    cl_fused_flags<<<NBLK, NTHR, 0, stream>>>(x, labels, centers, out, partial, flags);
}